// Round 2
// baseline (283.486 us; speedup 1.0000x reference)
//
#include <hip/hip_runtime.h>

// Problem constants
#define EMB  4096
#define DH   128      // QKV_DIM
#define NH   32       // N_HEADS
#define NTOK 16384    // B*S
#define NCOL 384      // qs | k | v columns

// GEMM tile
#define BM 128
#define BN 128
#define BK 32

typedef __attribute__((ext_vector_type(8))) short short8;
typedef __attribute__((ext_vector_type(4))) float f32x4;

// f32 -> bf16 bits, round-to-nearest-even (no NaN handling; inputs are finite)
static __device__ __forceinline__ unsigned short f2bf(float f) {
    unsigned int u = __builtin_bit_cast(unsigned int, f);
    u += 0x7fffu + ((u >> 16) & 1u);
    return (unsigned short)(u >> 16);
}
static __device__ __forceinline__ unsigned int cvt2(float a, float b) {
    return (unsigned int)f2bf(a) | ((unsigned int)f2bf(b) << 16);
}
// pack 8 f32 -> 8 bf16 (K-order preserved: x.x is element 0)
static __device__ __forceinline__ short8 cvt8(const float4& x, const float4& y) {
    union { short8 v; unsigned int u[4]; } r;
    r.u[0] = cvt2(x.x, x.y);
    r.u[1] = cvt2(x.z, x.w);
    r.u[2] = cvt2(y.x, y.y);
    r.u[3] = cvt2(y.z, y.w);
    return r.v;
}

// ---------------------------------------------------------------------------
// Kernel 1: build W3T (bf16, [384][4096], transposed weights) and bias[384].
//   n in [0,128):    W3T[n][D] = sum_h Wq[D][n][h]      bias[n] = sum_h bq[n][h]
//   n in [128,256):  W3T[n][D] = Wk[D][n-128]           bias[n] = bk[n-128]
//   n in [256,384):  W3T[n][D] = Wv[D][n-256]           bias[n] = bv[n-256]
// ---------------------------------------------------------------------------
__global__ void prep_w(const float* __restrict__ Wq, const float* __restrict__ bq,
                       const float* __restrict__ Wk, const float* __restrict__ bk,
                       const float* __restrict__ Wv, const float* __restrict__ bv,
                       unsigned short* __restrict__ W3T, float* __restrict__ bias) {
    const int gid = blockIdx.x * 256 + threadIdx.x;   // gid = n*EMB + D
    const int n = gid / EMB;
    const int D = gid - n * EMB;
    float val;
    if (n < DH) {
        // 32 contiguous f32 per thread (h fastest in Wq)
        const float4* p = (const float4*)(Wq + ((size_t)D * DH + n) * NH);
        float s = 0.f;
#pragma unroll
        for (int i = 0; i < 8; ++i) { float4 v = p[i]; s += (v.x + v.y) + (v.z + v.w); }
        val = s;
    } else if (n < 2 * DH) {
        val = Wk[(size_t)D * DH + (n - DH)];
    } else {
        val = Wv[(size_t)D * DH + (n - 2 * DH)];
    }
    W3T[gid] = f2bf(val);

    if (gid < NCOL) {
        float b;
        if (gid < DH) {
            float s = 0.f;
#pragma unroll
            for (int h = 0; h < NH; ++h) s += bq[gid * NH + h];
            b = s;
        } else if (gid < 2 * DH) {
            b = bk[gid - DH];
        } else {
            b = bv[gid - 2 * DH];
        }
        bias[gid] = b;
    }
}

// ---------------------------------------------------------------------------
// Kernel 2: qkv[token][0:384] = x[token][:] @ W3 + bias   (bf16 MFMA, f32 acc)
// 128x128 tile, BK=32, 4 waves (2x2), each wave 64x64 via 4x4 16x16x32 frags.
// ---------------------------------------------------------------------------
__global__ void gemm_qkv(const float* __restrict__ X,
                         const unsigned short* __restrict__ W3T,
                         const float* __restrict__ bias,
                         float* __restrict__ qkv) {
    __shared__ unsigned short Asm[BM * BK];   // [row][k], 8 KB
    __shared__ unsigned short Bsm[BN * BK];   // [n][k]  , 8 KB

    const int n0 = blockIdx.x * BN;           // x fastest: 3 N-tiles of one M-panel
    const int m0 = blockIdx.y * BM;           // dispatch adjacently -> share x in L2/L3
    const int t  = threadIdx.x;
    const int lane = t & 63;
    const int wid  = t >> 6;
    const int wr = wid >> 1, wc = wid & 1;    // 2x2 wave grid
    const int lmod = lane & 15, lgrp = lane >> 4;

    f32x4 acc[4][4] = {};

    // staging: each thread owns 16 elements of one row's K-chunk
    const int srow = t >> 1;
    const int skh  = (t & 1) * 16;
    const float*          xp = X   + (size_t)(m0 + srow) * EMB + skh;
    const unsigned short* wp = W3T + (size_t)(n0 + srow) * EMB + skh;

    // prefetch k0 = 0
    float4 a0 = *(const float4*)(xp + 0);
    float4 a1 = *(const float4*)(xp + 4);
    float4 a2 = *(const float4*)(xp + 8);
    float4 a3 = *(const float4*)(xp + 12);
    float4 b0 = *(const float4*)(wp + 0);   // 8 bf16
    float4 b1 = *(const float4*)(wp + 8);   // 8 bf16

    for (int k0 = 0; k0 < EMB; k0 += BK) {
        __syncthreads();
        *(short8*)(&Asm[srow * BK + skh])     = cvt8(a0, a1);
        *(short8*)(&Asm[srow * BK + skh + 8]) = cvt8(a2, a3);
        *(float4*)(&Bsm[srow * BK + skh])     = b0;
        *(float4*)(&Bsm[srow * BK + skh + 8]) = b1;
        __syncthreads();

        if (k0 + BK < EMB) {  // prefetch next tile; overlaps with MFMA below
            a0 = *(const float4*)(xp + k0 + BK + 0);
            a1 = *(const float4*)(xp + k0 + BK + 4);
            a2 = *(const float4*)(xp + k0 + BK + 8);
            a3 = *(const float4*)(xp + k0 + BK + 12);
            b0 = *(const float4*)(wp + k0 + BK + 0);
            b1 = *(const float4*)(wp + k0 + BK + 8);
        }

        short8 af[4], bf[4];
#pragma unroll
        for (int i = 0; i < 4; ++i)
            af[i] = *(const short8*)(&Asm[(wr * 64 + i * 16 + lmod) * BK + lgrp * 8]);
#pragma unroll
        for (int j = 0; j < 4; ++j)
            bf[j] = *(const short8*)(&Bsm[(wc * 64 + j * 16 + lmod) * BK + lgrp * 8]);
#pragma unroll
        for (int i = 0; i < 4; ++i)
#pragma unroll
            for (int j = 0; j < 4; ++j)
                acc[i][j] = __builtin_amdgcn_mfma_f32_16x16x32_bf16(af[i], bf[j], acc[i][j], 0, 0, 0);
    }

    // epilogue: C/D layout col = lane&15, row = (lane>>4)*4 + reg
#pragma unroll
    for (int j = 0; j < 4; ++j) {
        const int gcol = n0 + wc * 64 + j * 16 + lmod;
        const float bj = bias[gcol];
#pragma unroll
        for (int i = 0; i < 4; ++i) {
            const int grow = m0 + wr * 64 + i * 16 + lgrp * 4;
#pragma unroll
            for (int r = 0; r < 4; ++r)
                qkv[(size_t)(grow + r) * NCOL + gcol] = acc[i][j][r] + bj;
        }
    }
}

// ---------------------------------------------------------------------------
// Kernel 3: per token: o[d] = sum_e exp2(a_d*k_e - m_d) * v_e / sum_e exp2(...)
//   with a_d = qs[d] * scale * log2(e); m_d = a_d>=0 ? a_d*kmax : a_d*kmin.
// Then broadcast o[d] to 32 heads: out[token][d*32+h] = o[d].
// One wave per token, 4 tokens per block.
// ---------------------------------------------------------------------------
__global__ void attn_out(const float* __restrict__ qkv, float* __restrict__ out) {
    __shared__ float kvs[4][DH][2];
    __shared__ float osm[4][DH];
    const int t = threadIdx.x, lane = t & 63, w = t >> 6;
    const int token = blockIdx.x * 4 + w;
    const float* bp = qkv + (size_t)token * NCOL;

    const float q0  = bp[lane],       q1  = bp[64 + lane];
    const float kk0 = bp[128 + lane], kk1 = bp[192 + lane];
    const float vv0 = bp[256 + lane], vv1 = bp[320 + lane];
    kvs[w][lane][0]      = kk0;  kvs[w][lane][1]      = vv0;
    kvs[w][64 + lane][0] = kk1;  kvs[w][64 + lane][1] = vv1;

    float lmax = fmaxf(kk0, kk1), lmin = fminf(kk0, kk1);
#pragma unroll
    for (int off = 32; off; off >>= 1) {
        lmax = fmaxf(lmax, __shfl_xor(lmax, off));
        lmin = fminf(lmin, __shfl_xor(lmin, off));
    }
    __syncthreads();

    const float c  = 0.088388347648318447f * 1.4426950408889634f; // scale * log2(e)
    const float a0 = q0 * c, a1 = q1 * c;
    const float m0 = (a0 >= 0.f) ? a0 * lmax : a0 * lmin;
    const float m1 = (a1 >= 0.f) ? a1 * lmax : a1 * lmin;

    float s00 = 0.f, s01 = 0.f, s10 = 0.f, s11 = 0.f;
#pragma unroll 4
    for (int e = 0; e < DH; ++e) {
        const float2 kv = *(const float2*)&kvs[w][e][0];   // broadcast read
        const float p0 = exp2f(fmaf(a0, kv.x, -m0));
        const float p1 = exp2f(fmaf(a1, kv.x, -m1));
        s00 += p0;  s01 = fmaf(p0, kv.y, s01);
        s10 += p1;  s11 = fmaf(p1, kv.y, s11);
    }
    osm[w][lane]      = s01 / s00;
    osm[w][64 + lane] = s11 / s10;
    __syncthreads();

    float* orow = out + (size_t)token * (DH * NH);
#pragma unroll
    for (int it = 0; it < 16; ++it) {
        const int idx = it * 64 + lane;          // float4 index within the 4096-row
        const float val = osm[w][idx >> 3];      // d = (idx*4)/32
        float4 f4; f4.x = val; f4.y = val; f4.z = val; f4.w = val;
        *(float4*)(orow + idx * 4) = f4;
    }
}

// ---------------------------------------------------------------------------
extern "C" void kernel_launch(void* const* d_in, const int* in_sizes, int n_in,
                              void* d_out, int out_size, void* d_ws, size_t ws_size,
                              hipStream_t stream) {
    const float* x  = (const float*)d_in[0];
    const float* Wq = (const float*)d_in[1];
    const float* bq = (const float*)d_in[2];
    const float* Wk = (const float*)d_in[3];
    const float* bk = (const float*)d_in[4];
    const float* Wv = (const float*)d_in[5];
    const float* bv = (const float*)d_in[6];
    float* out = (float*)d_out;

    char* ws = (char*)d_ws;
    unsigned short* W3T = (unsigned short*)ws;                  // 384*4096*2 = 3,145,728 B
    float* bias = (float*)(ws + 3145728);                        // 1,536 B
    float* qkv  = (float*)(ws + 3145728 + 2048);                 // 16384*384*4 = 25,165,824 B

    prep_w<<<(NCOL * EMB) / 256, 256, 0, stream>>>(Wq, bq, Wk, bk, Wv, bv, W3T, bias);
    gemm_qkv<<<dim3(3, NTOK / BM), 256, 0, stream>>>(x, W3T, bias, qkv);
    attn_out<<<NTOK / 4, 256, 0, stream>>>(qkv, out);
}

// Round 3
// 259.086 us; speedup vs baseline: 1.0942x; 1.0942x over previous
//
#include <hip/hip_runtime.h>

// Problem constants
#define EMB  4096
#define DH   128      // QKV_DIM
#define NH   32       // N_HEADS
#define NTOK 16384    // B*S
#define NCOL 384      // qs | k | v columns

// GEMM tile
#define BM 64
#define BN 128
#define BK 32
#define LP (BK + 8)   // padded LDS row stride (shorts): 80 B = 20 banks

typedef __attribute__((ext_vector_type(8))) short short8;
typedef __attribute__((ext_vector_type(4))) float f32x4;

// f32 -> bf16 bits, round-to-nearest-even (no NaN handling; inputs are finite)
static __device__ __forceinline__ unsigned short f2bf(float f) {
    unsigned int u = __builtin_bit_cast(unsigned int, f);
    u += 0x7fffu + ((u >> 16) & 1u);
    return (unsigned short)(u >> 16);
}
static __device__ __forceinline__ unsigned int cvt2(float a, float b) {
    return (unsigned int)f2bf(a) | ((unsigned int)f2bf(b) << 16);
}
// pack 8 f32 -> 8 bf16 (K-order preserved: x.x is element 0)
static __device__ __forceinline__ short8 cvt8(const float4& x, const float4& y) {
    union { short8 v; unsigned int u[4]; } r;
    r.u[0] = cvt2(x.x, x.y);
    r.u[1] = cvt2(x.z, x.w);
    r.u[2] = cvt2(y.x, y.y);
    r.u[3] = cvt2(y.z, y.w);
    return r.v;
}

// ---------------------------------------------------------------------------
// Kernel 1: build W3T (bf16, [384][4096], transposed weights) and bias[384].
// ---------------------------------------------------------------------------
__global__ void prep_w(const float* __restrict__ Wq, const float* __restrict__ bq,
                       const float* __restrict__ Wk, const float* __restrict__ bk,
                       const float* __restrict__ Wv, const float* __restrict__ bv,
                       unsigned short* __restrict__ W3T, float* __restrict__ bias) {
    const int gid = blockIdx.x * 256 + threadIdx.x;   // gid = n*EMB + D
    const int n = gid / EMB;
    const int D = gid - n * EMB;
    float val;
    if (n < DH) {
        const float4* p = (const float4*)(Wq + ((size_t)D * DH + n) * NH);
        float s = 0.f;
#pragma unroll
        for (int i = 0; i < 8; ++i) { float4 v = p[i]; s += (v.x + v.y) + (v.z + v.w); }
        val = s;
    } else if (n < 2 * DH) {
        val = Wk[(size_t)D * DH + (n - DH)];
    } else {
        val = Wv[(size_t)D * DH + (n - 2 * DH)];
    }
    W3T[gid] = f2bf(val);

    if (gid < NCOL) {
        float b;
        if (gid < DH) {
            float s = 0.f;
#pragma unroll
            for (int h = 0; h < NH; ++h) s += bq[gid * NH + h];
            b = s;
        } else if (gid < 2 * DH) {
            b = bk[gid - DH];
        } else {
            b = bv[gid - 2 * DH];
        }
        bias[gid] = b;
    }
}

// ---------------------------------------------------------------------------
// Kernel 2: qkv = x @ W3 + bias  (bf16 MFMA, f32 acc)
// 64x128 tile, BK=32, 4 waves (2x2), wave tile 32x64 via 2x4 16x16x32 frags.
// 768 blocks = 3/CU (12 waves/CU); XCD-chunked so the 3 N-tiles of one
// x M-panel are co-XCD; LDS rows padded to 20 banks (no 8-way conflicts).
// ---------------------------------------------------------------------------
__global__ __launch_bounds__(256) void gemm_qkv(const float* __restrict__ X,
                         const unsigned short* __restrict__ W3T,
                         const float* __restrict__ bias,
                         float* __restrict__ qkv) {
    __shared__ unsigned short Asm[BM * LP];   // [row][k] padded
    __shared__ unsigned short Bsm[BN * LP];

    // XCD-aware bijective remap: 768 work items, 96 per XCD (768 % 8 == 0)
    const int bid  = blockIdx.x;
    const int xcd  = bid & 7;
    const int slot = bid >> 3;
    const int wkid = xcd * 96 + slot;         // XCD c owns [96c, 96c+96)
    const int my   = wkid / 3;                // N fastest: 3 N-tiles adjacent
    const int mx   = wkid - my * 3;
    const int m0 = my * BM;
    const int n0 = mx * BN;

    const int t  = threadIdx.x;
    const int lane = t & 63;
    const int wid  = t >> 6;
    const int wr = wid >> 1, wc = wid & 1;    // 2x2 wave grid, wave tile 32x64
    const int lmod = lane & 15, lgrp = lane >> 4;

    f32x4 acc[2][4] = {};

    // A staging: 64 rows x 32 k; thread t owns row t>>2, k-chunk (t&3)*8
    const int arow = t >> 2, akh = (t & 3) * 8;
    // B staging: 128 rows x 32 k; thread t owns row t>>1, k-chunk (t&1)*16
    const int brow = t >> 1, bkh = (t & 1) * 16;
    const float*          xp = X   + (size_t)(m0 + arow) * EMB + akh;
    const unsigned short* wp = W3T + (size_t)(n0 + brow) * EMB + bkh;

    // prefetch k0 = 0
    float4 a0 = *(const float4*)(xp + 0);
    float4 a1 = *(const float4*)(xp + 4);
    float4 b0 = *(const float4*)(wp + 0);   // 8 bf16
    float4 b1 = *(const float4*)(wp + 8);   // 8 bf16

    for (int k0 = 0; k0 < EMB; k0 += BK) {
        __syncthreads();
        *(short8*)(&Asm[arow * LP + akh])     = cvt8(a0, a1);
        *(float4*)(&Bsm[brow * LP + bkh])     = b0;
        *(float4*)(&Bsm[brow * LP + bkh + 8]) = b1;
        __syncthreads();

        if (k0 + BK < EMB) {  // prefetch next tile; overlaps with MFMA below
            a0 = *(const float4*)(xp + k0 + BK + 0);
            a1 = *(const float4*)(xp + k0 + BK + 4);
            b0 = *(const float4*)(wp + k0 + BK + 0);
            b1 = *(const float4*)(wp + k0 + BK + 8);
        }

        short8 af[2], bf[4];
#pragma unroll
        for (int i = 0; i < 2; ++i)
            af[i] = *(const short8*)(&Asm[(wr * 32 + i * 16 + lmod) * LP + lgrp * 8]);
#pragma unroll
        for (int j = 0; j < 4; ++j)
            bf[j] = *(const short8*)(&Bsm[(wc * 64 + j * 16 + lmod) * LP + lgrp * 8]);
#pragma unroll
        for (int i = 0; i < 2; ++i)
#pragma unroll
            for (int j = 0; j < 4; ++j)
                acc[i][j] = __builtin_amdgcn_mfma_f32_16x16x32_bf16(af[i], bf[j], acc[i][j], 0, 0, 0);
    }

    // epilogue: C/D layout col = lane&15, row = (lane>>4)*4 + reg
#pragma unroll
    for (int j = 0; j < 4; ++j) {
        const int gcol = n0 + wc * 64 + j * 16 + lmod;
        const float bj = bias[gcol];
#pragma unroll
        for (int i = 0; i < 2; ++i) {
            const int grow = m0 + wr * 32 + i * 16 + lgrp * 4;
#pragma unroll
            for (int r = 0; r < 4; ++r)
                qkv[(size_t)(grow + r) * NCOL + gcol] = acc[i][j][r] + bj;
        }
    }
}

// ---------------------------------------------------------------------------
// Kernel 3: per token: o[d] = sum_e exp2(a_d*k_e - m_d) * v_e / sum_e exp2(...)
// Broadcast o[d] to 32 heads. One wave per token, 4 tokens per block.
// ---------------------------------------------------------------------------
__global__ void attn_out(const float* __restrict__ qkv, float* __restrict__ out) {
    __shared__ float kvs[4][DH][2];
    __shared__ float osm[4][DH];
    const int t = threadIdx.x, lane = t & 63, w = t >> 6;
    const int token = blockIdx.x * 4 + w;
    const float* bp = qkv + (size_t)token * NCOL;

    const float q0  = bp[lane],       q1  = bp[64 + lane];
    const float kk0 = bp[128 + lane], kk1 = bp[192 + lane];
    const float vv0 = bp[256 + lane], vv1 = bp[320 + lane];
    kvs[w][lane][0]      = kk0;  kvs[w][lane][1]      = vv0;
    kvs[w][64 + lane][0] = kk1;  kvs[w][64 + lane][1] = vv1;

    float lmax = fmaxf(kk0, kk1), lmin = fminf(kk0, kk1);
#pragma unroll
    for (int off = 32; off; off >>= 1) {
        lmax = fmaxf(lmax, __shfl_xor(lmax, off));
        lmin = fminf(lmin, __shfl_xor(lmin, off));
    }
    __syncthreads();

    const float c  = 0.088388347648318447f * 1.4426950408889634f; // scale * log2(e)
    const float a0 = q0 * c, a1 = q1 * c;
    const float m0 = (a0 >= 0.f) ? a0 * lmax : a0 * lmin;
    const float m1 = (a1 >= 0.f) ? a1 * lmax : a1 * lmin;

    float s00 = 0.f, s01 = 0.f, s10 = 0.f, s11 = 0.f;
#pragma unroll 4
    for (int e = 0; e < DH; ++e) {
        const float2 kv = *(const float2*)&kvs[w][e][0];   // broadcast read
        const float p0 = exp2f(fmaf(a0, kv.x, -m0));
        const float p1 = exp2f(fmaf(a1, kv.x, -m1));
        s00 += p0;  s01 = fmaf(p0, kv.y, s01);
        s10 += p1;  s11 = fmaf(p1, kv.y, s11);
    }
    osm[w][lane]      = s01 / s00;
    osm[w][64 + lane] = s11 / s10;
    __syncthreads();

    float* orow = out + (size_t)token * (DH * NH);
#pragma unroll
    for (int it = 0; it < 16; ++it) {
        const int idx = it * 64 + lane;          // float4 index within the 4096-row
        const float val = osm[w][idx >> 3];      // d = (idx*4)/32
        float4 f4; f4.x = val; f4.y = val; f4.z = val; f4.w = val;
        *(float4*)(orow + idx * 4) = f4;
    }
}

// ---------------------------------------------------------------------------
extern "C" void kernel_launch(void* const* d_in, const int* in_sizes, int n_in,
                              void* d_out, int out_size, void* d_ws, size_t ws_size,
                              hipStream_t stream) {
    const float* x  = (const float*)d_in[0];
    const float* Wq = (const float*)d_in[1];
    const float* bq = (const float*)d_in[2];
    const float* Wk = (const float*)d_in[3];
    const float* bk = (const float*)d_in[4];
    const float* Wv = (const float*)d_in[5];
    const float* bv = (const float*)d_in[6];
    float* out = (float*)d_out;

    char* ws = (char*)d_ws;
    unsigned short* W3T = (unsigned short*)ws;                  // 384*4096*2 = 3,145,728 B
    float* bias = (float*)(ws + 3145728);                        // 1,536 B
    float* qkv  = (float*)(ws + 3145728 + 2048);                 // 16384*384*4 = 25,165,824 B

    prep_w<<<(NCOL * EMB) / 256, 256, 0, stream>>>(Wq, bq, Wk, bk, Wv, bv, W3T, bias);
    gemm_qkv<<<(NCOL / BN) * (NTOK / BM), 256, 0, stream>>>(x, W3T, bias, qkv);
    attn_out<<<NTOK / 4, 256, 0, stream>>>(qkv, out);
}

// Round 4
// 244.660 us; speedup vs baseline: 1.1587x; 1.0590x over previous
//
#include <hip/hip_runtime.h>

// Problem constants
#define EMB  4096
#define DH   128      // QKV_DIM
#define NH   32       // N_HEADS
#define NTOK 16384    // B*S
#define NCOL 384      // qs | k | v columns

// GEMM tile: 128x128 block, BK=64, 4 waves (2x2), wave tile 64x64 (acc 4x4)
#define BM 128
#define BN 128
#define BK 64

typedef __attribute__((ext_vector_type(8))) short short8;
typedef __attribute__((ext_vector_type(4))) float f32x4;

// f32 pair -> packed bf16x2, RNE (hardware cvt)
static __device__ __forceinline__ unsigned int cvt2(float a, float b) {
    unsigned int r;
    asm volatile("v_cvt_pk_bf16_f32 %0, %1, %2" : "=v"(r) : "v"(a), "v"(b));
    return r;
}
// pack 8 f32 -> 8 bf16 (K-order preserved)
static __device__ __forceinline__ short8 cvt8(const float4& x, const float4& y) {
    union { short8 v; unsigned int u[4]; } r;
    r.u[0] = cvt2(x.x, x.y);
    r.u[1] = cvt2(x.z, x.w);
    r.u[2] = cvt2(y.x, y.y);
    r.u[3] = cvt2(y.z, y.w);
    return r.v;
}
// scalar f32 -> bf16 bits, RNE (prep_w only)
static __device__ __forceinline__ unsigned short f2bf(float f) {
    unsigned int u = __builtin_bit_cast(unsigned int, f);
    u += 0x7fffu + ((u >> 16) & 1u);
    return (unsigned short)(u >> 16);
}
// async global->LDS, 16B per lane; LDS dest is wave-uniform base + lane*16
static __device__ __forceinline__ void gload_lds16(const void* g, void* l) {
    __builtin_amdgcn_global_load_lds(
        (const __attribute__((address_space(1))) unsigned int*)g,
        (__attribute__((address_space(3))) unsigned int*)l, 16, 0, 0);
}

// ---------------------------------------------------------------------------
// Kernel 1: build W3T (bf16, [384][4096], transposed weights) and bias[384].
// ---------------------------------------------------------------------------
__global__ void prep_w(const float* __restrict__ Wq, const float* __restrict__ bq,
                       const float* __restrict__ Wk, const float* __restrict__ bk,
                       const float* __restrict__ Wv, const float* __restrict__ bv,
                       unsigned short* __restrict__ W3T, float* __restrict__ bias) {
    const int gid = blockIdx.x * 256 + threadIdx.x;   // gid = n*EMB + D
    const int n = gid / EMB;
    const int D = gid - n * EMB;
    float val;
    if (n < DH) {
        const float4* p = (const float4*)(Wq + ((size_t)D * DH + n) * NH);
        float s = 0.f;
#pragma unroll
        for (int i = 0; i < 8; ++i) { float4 v = p[i]; s += (v.x + v.y) + (v.z + v.w); }
        val = s;
    } else if (n < 2 * DH) {
        val = Wk[(size_t)D * DH + (n - DH)];
    } else {
        val = Wv[(size_t)D * DH + (n - 2 * DH)];
    }
    W3T[gid] = f2bf(val);

    if (gid < NCOL) {
        float b;
        if (gid < DH) {
            float s = 0.f;
#pragma unroll
            for (int h = 0; h < NH; ++h) s += bq[gid * NH + h];
            b = s;
        } else if (gid < 2 * DH) {
            b = bk[gid - DH];
        } else {
            b = bv[gid - 2 * DH];
        }
        bias[gid] = b;
    }
}

// ---------------------------------------------------------------------------
// Kernel 2: qkv_partial[ks] = x[:, ks-half] @ W3[ks-half, :]   (no bias here)
// m97 structure: single-buffered LDS, 2 barriers/iter, B via global_load_lds
// (pre-swizzled source chunks), A reg-staged f32->bf16 (swizzled write).
// Chunk swizzle: 16B chunk c of row r lives at LDS chunk c ^ (r&7)  -> the
// 16-lane fragment read (rows r..r+15, same k-chunk) spreads over all banks.
// ---------------------------------------------------------------------------
__global__ __launch_bounds__(256) void gemm_qkv(const float* __restrict__ X,
                         const unsigned short* __restrict__ W3T,
                         float* __restrict__ qkvp, int nsplit) {
    __shared__ __align__(16) unsigned short Asm[BM * BK];   // 16 KB
    __shared__ __align__(16) unsigned short Bsm[BN * BK];   // 16 KB

    // XCD-bijective remap over 384*nsplit blocks (384 % 8 == 0)
    const int nblk  = 384 * nsplit;
    const int chnk  = nblk >> 3;
    const int bid   = blockIdx.x;
    const int wkid  = (bid & 7) * chnk + (bid >> 3);
    const int ks    = wkid / 384;
    const int rem   = wkid - ks * 384;
    const int my    = rem / 3;
    const int mx    = rem - my * 3;
    const int m0 = my * BM, n0 = mx * BN;
    const int klen = EMB / nsplit;
    const int koff = ks * klen;

    const int t = threadIdx.x, lane = t & 63, wid = t >> 6;
    const int wr = wid >> 1, wc = wid & 1;        // 2x2 wave grid, 64x64 tiles
    const int lmod = lane & 15, lgrp = lane >> 4;

    f32x4 acc[4][4] = {};

    // A staging: thread owns row t>>1, 32 f32 at chunk base (t&1)*4
    const int arow = t >> 1;
    const int acb  = (t & 1) * 4;
    const float* xp = X + (size_t)(m0 + arow) * EMB + koff + acb * 8;

    // B staging: wave stages rows wid*32..+32 in 4 issues of 8 rows;
    // lane -> row_local = lane>>3, LDS chunk = lane&7, src chunk = (lane&7)^(lane>>3)
    const int bro = lane >> 3;
    const int bch = (lane & 7) ^ bro;
    const unsigned short* wp = W3T + (size_t)(n0 + wid * 32 + bro) * EMB + koff + bch * 8;
    unsigned short* bdst = &Bsm[(wid * 32) * BK];

    // prefetch A regs for k0 = 0
    float4 av[8];
#pragma unroll
    for (int i = 0; i < 8; ++i) av[i] = *(const float4*)(xp + i * 4);

    for (int k0 = 0; k0 < klen; k0 += BK) {
        __syncthreads();                          // all waves done reading prev tile
        // stage B (async, straight to LDS, linear dest)
#pragma unroll
        for (int i8 = 0; i8 < 4; ++i8)
            gload_lds16(wp + (size_t)i8 * 8 * EMB + k0, bdst + i8 * 8 * BK);
        // stage A (cvt + swizzled ds_write)
#pragma unroll
        for (int i = 0; i < 4; ++i) {
            const int c = (acb + i) ^ (arow & 7);
            *(short8*)(&Asm[arow * BK + c * 8]) = cvt8(av[2 * i], av[2 * i + 1]);
        }
        asm volatile("s_waitcnt vmcnt(0)" ::: "memory");
        __syncthreads();                          // tile fully staged

        // prefetch next A tile (latency hides under MFMA below)
        if (k0 + BK < klen) {
#pragma unroll
            for (int i = 0; i < 8; ++i) av[i] = *(const float4*)(xp + k0 + BK + i * 4);
        }

        // compute: 2 k-halves x (4x4) MFMA
#pragma unroll
        for (int kh = 0; kh < 2; ++kh) {
            const int cs = ((kh * 4 + lgrp) ^ (lmod & 7)) * 8;
            short8 af[4], bf[4];
#pragma unroll
            for (int i = 0; i < 4; ++i)
                af[i] = *(const short8*)(&Asm[(wr * 64 + i * 16 + lmod) * BK + cs]);
#pragma unroll
            for (int j = 0; j < 4; ++j)
                bf[j] = *(const short8*)(&Bsm[(wc * 64 + j * 16 + lmod) * BK + cs]);
#pragma unroll
            for (int i = 0; i < 4; ++i)
#pragma unroll
                for (int j = 0; j < 4; ++j)
                    acc[i][j] = __builtin_amdgcn_mfma_f32_16x16x32_bf16(af[i], bf[j], acc[i][j], 0, 0, 0);
        }
    }

    // epilogue: C/D layout col = lane&15, row = (lane>>4)*4 + reg
    float* outp = qkvp + (size_t)ks * NTOK * NCOL;
#pragma unroll
    for (int j = 0; j < 4; ++j) {
        const int gcol = n0 + wc * 64 + j * 16 + lmod;
#pragma unroll
        for (int i = 0; i < 4; ++i) {
            const int grow = m0 + wr * 64 + i * 16 + (lgrp << 2);
#pragma unroll
            for (int r = 0; r < 4; ++r)
                outp[(size_t)(grow + r) * NCOL + gcol] = acc[i][j][r];
        }
    }
}

// ---------------------------------------------------------------------------
// Kernel 3: sum split-K partials + bias, per-token rank-1 softmax, broadcast.
// One wave per token, 4 tokens per block.
// ---------------------------------------------------------------------------
__global__ void attn_out(const float* __restrict__ qkv0, const float* __restrict__ qkv1,
                         const float* __restrict__ bias, float* __restrict__ out,
                         int nsplit) {
    __shared__ float kvs[4][DH][2];
    __shared__ float osm[4][DH];
    const int t = threadIdx.x, lane = t & 63, w = t >> 6;
    const int token = blockIdx.x * 4 + w;
    const float* b0 = qkv0 + (size_t)token * NCOL;

    float q0  = b0[lane],       q1  = b0[64 + lane];
    float kk0 = b0[128 + lane], kk1 = b0[192 + lane];
    float vv0 = b0[256 + lane], vv1 = b0[320 + lane];
    if (nsplit == 2) {
        const float* b1 = qkv1 + (size_t)token * NCOL;
        q0  += b1[lane];       q1  += b1[64 + lane];
        kk0 += b1[128 + lane]; kk1 += b1[192 + lane];
        vv0 += b1[256 + lane]; vv1 += b1[320 + lane];
    }
    q0  += bias[lane];       q1  += bias[64 + lane];
    kk0 += bias[128 + lane]; kk1 += bias[192 + lane];
    vv0 += bias[256 + lane]; vv1 += bias[320 + lane];

    kvs[w][lane][0]      = kk0;  kvs[w][lane][1]      = vv0;
    kvs[w][64 + lane][0] = kk1;  kvs[w][64 + lane][1] = vv1;

    float lmax = fmaxf(kk0, kk1), lmin = fminf(kk0, kk1);
#pragma unroll
    for (int off = 32; off; off >>= 1) {
        lmax = fmaxf(lmax, __shfl_xor(lmax, off));
        lmin = fminf(lmin, __shfl_xor(lmin, off));
    }
    __syncthreads();

    const float c  = 0.088388347648318447f * 1.4426950408889634f; // scale * log2(e)
    const float a0 = q0 * c, a1 = q1 * c;
    const float m0 = (a0 >= 0.f) ? a0 * lmax : a0 * lmin;
    const float m1 = (a1 >= 0.f) ? a1 * lmax : a1 * lmin;

    float s00 = 0.f, s01 = 0.f, s10 = 0.f, s11 = 0.f;
#pragma unroll 4
    for (int e = 0; e < DH; ++e) {
        const float2 kv = *(const float2*)&kvs[w][e][0];   // broadcast read
        const float p0 = exp2f(fmaf(a0, kv.x, -m0));
        const float p1 = exp2f(fmaf(a1, kv.x, -m1));
        s00 += p0;  s01 = fmaf(p0, kv.y, s01);
        s10 += p1;  s11 = fmaf(p1, kv.y, s11);
    }
    osm[w][lane]      = s01 / s00;
    osm[w][64 + lane] = s11 / s10;
    __syncthreads();

    float* orow = out + (size_t)token * (DH * NH);
#pragma unroll
    for (int it = 0; it < 16; ++it) {
        const int idx = it * 64 + lane;          // float4 index within the 4096-row
        const float val = osm[w][idx >> 3];      // d = (idx*4)/32
        float4 f4; f4.x = val; f4.y = val; f4.z = val; f4.w = val;
        *(float4*)(orow + idx * 4) = f4;
    }
}

// ---------------------------------------------------------------------------
extern "C" void kernel_launch(void* const* d_in, const int* in_sizes, int n_in,
                              void* d_out, int out_size, void* d_ws, size_t ws_size,
                              hipStream_t stream) {
    const float* x  = (const float*)d_in[0];
    const float* Wq = (const float*)d_in[1];
    const float* bq = (const float*)d_in[2];
    const float* Wk = (const float*)d_in[3];
    const float* bk = (const float*)d_in[4];
    const float* Wv = (const float*)d_in[5];
    const float* bv = (const float*)d_in[6];
    float* out = (float*)d_out;

    char* ws = (char*)d_ws;
    const size_t off_bias = 3145728;                 // W3T: 384*4096*2
    const size_t off_q0   = off_bias + 4096;
    const size_t off_q1   = off_q0 + (size_t)NTOK * NCOL * 4;
    const size_t need2    = off_q1 + (size_t)NTOK * NCOL * 4;  // 53,481,472 B

    unsigned short* W3T = (unsigned short*)ws;
    float* bias = (float*)(ws + off_bias);
    float* qkv0 = (float*)(ws + off_q0);
    const int nsplit = (ws_size >= need2) ? 2 : 1;
    float* qkv1 = (nsplit == 2) ? (float*)(ws + off_q1) : qkv0;

    prep_w<<<(NCOL * EMB) / 256, 256, 0, stream>>>(Wq, bq, Wk, bk, Wv, bv, W3T, bias);
    gemm_qkv<<<384 * nsplit, 256, 0, stream>>>(x, W3T, qkv0, nsplit);
    attn_out<<<NTOK / 4, 256, 0, stream>>>(qkv0, qkv1, bias, out, nsplit);
}